// Round 7
// baseline (146.842 us; speedup 1.0000x reference)
//
#include <hip/hip_runtime.h>
#include <hip/hip_bf16.h>

// R7: fuse all three phases into ONE persistent kernel (256 blocks = 1/CU,
// guaranteed co-residency) with two device-fence grid barriers. R6 analysis:
// per-graph-node overhead ~4-5 us dominates our controllable time (kernel
// busy-cycle model ~10-12 us vs ~43 us observed across 3 nodes). Phase
// bodies verbatim from R6 (absmax 0.03125). Barrier counters live in d_ws
// (0xAA-poisoned): race-free init via atomicCAS(cnt, 0xAAAAAAAA, 0) from
// every block — atomics on one line serialize, every block's first op is the
// CAS, so the first toucher resets; 0-initialized state also handled.

typedef short bf16x8 __attribute__((ext_vector_type(8)));
typedef float f32x4 __attribute__((ext_vector_type(4)));

#define NPAIR_UNITS 544
#define NBLOCKS 256
#define POISON32 0xAAAAAAAAu

__device__ __forceinline__ float wave_sum(float v) {
#pragma unroll
  for (int off = 32; off; off >>= 1) v += __shfl_xor(v, off);
  return v;
}

__device__ __forceinline__ unsigned short f2bf(float x) {  // RNE, finite inputs
  union { float f; unsigned u; } v; v.f = x;
  return (unsigned short)((v.u + 0x7fffu + ((v.u >> 16) & 1u)) >> 16);
}
__device__ __forceinline__ float bf2f(unsigned short h) {
  union { float f; unsigned u; } v; v.u = ((unsigned)h) << 16;
  return v.f;
}

// Grid barrier: release-fence + count; thread 0 spins, block joins at sync.
__device__ __forceinline__ void grid_barrier(unsigned* cnt) {
  __syncthreads();
  if (threadIdx.x == 0) {
    __threadfence();            // release: this block's writes -> device scope
    atomicAdd(cnt, 1u);
    while (__hip_atomic_load(cnt, __ATOMIC_RELAXED, __HIP_MEMORY_SCOPE_AGENT) <
           (unsigned)NBLOCKS)
      __builtin_amdgcn_s_sleep(8);
    __threadfence();            // acquire: other blocks' writes visible
  }
  __syncthreads();
}

// One wave: gumbel-softmax for 16 rows (K=128) -> A-fragments in-register ->
// acc += S @ W^T (16 MFMAs). lgp/nzp pre-offset to (row, part*8): lane
// (r,part) covers columns ks*32 + part*8 + j == its A-fragment slices.
// Cross-lane traffic = softmax denominator only (shfl_xor; no LDS/barrier).
__device__ __forceinline__ void gumbel_mfma(const float* __restrict__ lgp,
                                            const float* __restrict__ nzp,
                                            const bf16x8 Bf[4][4], f32x4 acc[4]) {
  float e[32];
  float ps = 0.0f;
#pragma unroll
  for (int ks = 0; ks < 4; ++ks) {
#pragma unroll
    for (int h = 0; h < 2; ++h) {
      float4 L = *(const float4*)(lgp + ks * 32 + h * 4);
      float4 U = *(const float4*)(nzp + ks * 32 + h * 4);
      float lv[4] = {L.x, L.y, L.z, L.w};
      float uv[4] = {U.x, U.y, U.z, U.w};
#pragma unroll
      for (int j = 0; j < 4; ++j) {
        float g = -__logf(-__logf(uv[j] + 1e-9f) + 1e-9f);
        float ev = __expf(lv[j] + g);
        e[ks * 8 + h * 4 + j] = ev;
        ps += ev;
      }
    }
  }
  ps += __shfl_xor(ps, 16);
  ps += __shfl_xor(ps, 32);
  float inv = __builtin_amdgcn_rcpf(ps);
#pragma unroll
  for (int ks = 0; ks < 4; ++ks) {
    union { bf16x8 v; unsigned short s[8]; } pk;
#pragma unroll
    for (int j = 0; j < 8; ++j) pk.s[j] = f2bf(e[ks * 8 + j] * inv);
#pragma unroll
    for (int nt = 0; nt < 4; ++nt)
      acc[nt] = __builtin_amdgcn_mfma_f32_16x16x32_bf16(pk.v, Bf[nt][ks], acc[nt], 0, 0, 0);
  }
}

__global__ __launch_bounds__(256) void topicsne_fused(
    const float* __restrict__ logits, const float* __restrict__ noise_f,
    const float* __restrict__ noise_i, const float* __restrict__ noise_j,
    const float* __restrict__ topic_w, const float* __restrict__ tb,
    const int* __restrict__ ii, const int* __restrict__ jj,
    const float* __restrict__ pij, unsigned short* __restrict__ xb,
    float* __restrict__ sq, float* __restrict__ denomS,
    float* __restrict__ partial, unsigned* __restrict__ c1,
    unsigned* __restrict__ c2, float* __restrict__ out) {
  __shared__ float red[4];
  int w = threadIdx.x >> 6, lane = threadIdx.x & 63;
  int r = lane & 15, part = lane >> 4;

  // Barrier-counter init under 0xAA poison (see header comment).
  if (threadIdx.x == 0) {
    atomicCAS(c1, POISON32, 0u);
    atomicCAS(c2, POISON32, 0u);
  }

  // ---------------- Phase A: row engine (verbatim R6 row_engine) ----------
  {
    int wid = blockIdx.x * 4 + w;
    // B fragments: lane (r,part), step ks:
    // B[k = ks*32 + part*8 + j][n = nt*16 + r] = topic_w[n*128 + k].
    bf16x8 Bf[4][4];
#pragma unroll
    for (int nt = 0; nt < 4; ++nt) {
      const float* wp = topic_w + (nt * 16 + r) * 128 + part * 8;
#pragma unroll
      for (int ks = 0; ks < 4; ++ks) {
        float4 w0 = *(const float4*)(wp + ks * 32);
        float4 w1 = *(const float4*)(wp + ks * 32 + 4);
        union { bf16x8 v; unsigned short s[8]; } pk;
        pk.s[0] = f2bf(w0.x); pk.s[1] = f2bf(w0.y); pk.s[2] = f2bf(w0.z); pk.s[3] = f2bf(w0.w);
        pk.s[4] = f2bf(w1.x); pk.s[5] = f2bf(w1.y); pk.s[6] = f2bf(w1.z); pk.s[7] = f2bf(w1.w);
        Bf[nt][ks] = pk.v;
      }
    }
    int grp = wid >> 1;
    if ((wid & 1) == 0) {
      // x-type: rows g16..g16+15. C-layout: row m = part*4+g, col n = nt*16+r.
      int g16 = grp * 16;
      float tbv[4];
#pragma unroll
      for (int nt = 0; nt < 4; ++nt) tbv[nt] = tb[nt * 16 + r];
      f32x4 acc[4] = {};
      gumbel_mfma(logits + (g16 + r) * 128 + part * 8,
                  noise_f + (g16 + r) * 128 + part * 8, Bf, acc);
      float sqp[4] = {0.f, 0.f, 0.f, 0.f};
#pragma unroll
      for (int nt = 0; nt < 4; ++nt)
#pragma unroll
        for (int g = 0; g < 4; ++g) {
          unsigned short hb = f2bf(acc[nt][g] + tbv[nt]);
          xb[(g16 + part * 4 + g) * 64 + nt * 16 + r] = hb;
          float xr = bf2f(hb);  // rounded -> sq consistent with Gram dot
          sqp[g] += xr * xr;
        }
#pragma unroll
      for (int m = 1; m < 16; m <<= 1)
#pragma unroll
        for (int g = 0; g < 4; ++g) sqp[g] += __shfl_xor(sqp[g], m);
      if (r == 0) {
#pragma unroll
        for (int g = 0; g < 4; ++g) sq[g16 + part * 4 + g] = sqp[g];
      }
    } else {
      // pair-type: denom = 64 + ||xi-xj||^2 (bias cancels in the diff).
      int b0 = grp * 16;
      int rowi = ii[b0 + r], rowj = jj[b0 + r];
      f32x4 ai[4] = {}, aj[4] = {};
      gumbel_mfma(logits + rowi * 128 + part * 8,
                  noise_i + (b0 + r) * 128 + part * 8, Bf, ai);
      gumbel_mfma(logits + rowj * 128 + part * 8,
                  noise_j + (b0 + r) * 128 + part * 8, Bf, aj);
      float dp[4] = {0.f, 0.f, 0.f, 0.f};
#pragma unroll
      for (int nt = 0; nt < 4; ++nt)
#pragma unroll
        for (int g = 0; g < 4; ++g) {
          float d = ai[nt][g] - aj[nt][g];
          dp[g] += d * d;
        }
#pragma unroll
      for (int m = 1; m < 16; m <<= 1)
#pragma unroll
        for (int g = 0; g < 4; ++g) dp[g] += __shfl_xor(dp[g], m);
      if (r == 0) {
#pragma unroll
        for (int g = 0; g < 4; ++g) denomS[b0 + part * 4 + g] = 64.0f + dp[g];
      }
    }
  }

  grid_barrier(c1);  // xb/sq/denomS -> device scope; all blocks see them

  // ---------------- Phase B: triangular pairwise (R6 body, 544 units) -----
  int wr = w >> 1, wc = w & 1;
  int r0 = lane & 15, kq = lane >> 4;
  for (int u = blockIdx.x; u < NPAIR_UNITS; u += NBLOCKS) {
    // decode u -> (bi, cj0): bi row-band, chunks of 4 over bj in [bi,63]
    int b = u, bi = 0, nch = 16;
    while (b >= nch) { b -= nch; ++bi; nch = (64 - bi + 3) >> 2; }
    int cj0 = bi + (b << 2);
    int R = bi * 128 + wr * 64;

    bf16x8 A[4][2];
#pragma unroll
    for (int a = 0; a < 4; ++a)
#pragma unroll
      for (int s = 0; s < 2; ++s)
        A[a][s] = *(const bf16x8*)(xb + (R + a * 16 + r0) * 64 + s * 32 + kq * 8);
    float m1[4][4];
#pragma unroll
    for (int a = 0; a < 4; ++a)
#pragma unroll
      for (int g = 0; g < 4; ++g) m1[a][g] = 1.0f + sq[R + a * 16 + kq * 4 + g];

    float local = 0.0f;
    int bjEnd = min(cj0 + 4, 64);
    int bj = cj0;
    if (cj0 == bi && wr > wc) ++bj;  // lower-left wave of diag tile: skip
    if (bj < bjEnd) {
      bf16x8 Bc[4][2];
      float nsqc[4];
      {
        int C = bj * 128 + wc * 64;
#pragma unroll
        for (int a = 0; a < 4; ++a)
#pragma unroll
          for (int s = 0; s < 2; ++s)
            Bc[a][s] = *(const bf16x8*)(xb + (C + a * 16 + r0) * 64 + s * 32 + kq * 8);
#pragma unroll
        for (int q = 0; q < 4; ++q) nsqc[q] = sq[C + q * 16 + r0];
      }
      for (; bj < bjEnd; ++bj) {
        bool hasNext = (bj + 1) < bjEnd;
        bf16x8 Bn[4][2];
        float nsqn[4];
        if (hasNext) {  // prefetch next tile under this tile's compute
          int Cn = (bj + 1) * 128 + wc * 64;
#pragma unroll
          for (int a = 0; a < 4; ++a)
#pragma unroll
            for (int s = 0; s < 2; ++s)
              Bn[a][s] = *(const bf16x8*)(xb + (Cn + a * 16 + r0) * 64 + s * 32 + kq * 8);
#pragma unroll
          for (int q = 0; q < 4; ++q) nsqn[q] = sq[Cn + q * 16 + r0];
        }

        f32x4 acc[4][4] = {};
#pragma unroll
        for (int a = 0; a < 4; ++a)
#pragma unroll
          for (int q = 0; q < 4; ++q) {
            acc[a][q] = __builtin_amdgcn_mfma_f32_16x16x32_bf16(A[a][0], Bc[q][0], acc[a][q], 0, 0, 0);
            acc[a][q] = __builtin_amdgcn_mfma_f32_16x16x32_bf16(A[a][1], Bc[q][1], acc[a][q], 0, 0, 0);
          }

        if (bj == bi && wr == wc) {  // diagonal-straddling tile: r<c only
#pragma unroll
          for (int a = 0; a < 4; ++a)
#pragma unroll
            for (int q = 0; q < 4; ++q)
#pragma unroll
              for (int g = 0; g < 4; ++g) {
                float d = fmaf(-2.0f, acc[a][q][g], m1[a][g] + nsqc[q]);
                int rl = a * 16 + kq * 4 + g, cl = q * 16 + r0;
                local += (rl < cl) ? __builtin_amdgcn_rcpf(d) : 0.0f;
              }
        } else {
#pragma unroll
          for (int a = 0; a < 4; ++a)
#pragma unroll
            for (int q = 0; q < 4; ++q)
#pragma unroll
              for (int g = 0; g < 4; ++g) {
                float d = fmaf(-2.0f, acc[a][q][g], m1[a][g] + nsqc[q]);
                local += __builtin_amdgcn_rcpf(d);
              }
        }

        if (hasNext) {
#pragma unroll
          for (int a = 0; a < 4; ++a)
#pragma unroll
            for (int s = 0; s < 2; ++s) Bc[a][s] = Bn[a][s];
#pragma unroll
          for (int q = 0; q < 4; ++q) nsqc[q] = nsqn[q];
        }
      }
    }
    local = wave_sum(local);
    if (lane == 0) red[w] = local;
    __syncthreads();
    if (threadIdx.x == 0) partial[u] = red[0] + red[1] + red[2] + red[3];
    __syncthreads();  // red[] reused next unit
  }

  grid_barrier(c2);  // all partial[] -> device scope

  // ---------------- Phase C: finalize (256 blocks x 32 outputs) -----------
  {
    float ps = 0.0f;
    for (int k = threadIdx.x; k < NPAIR_UNITS; k += 256) ps += partial[k];
    ps = wave_sum(ps);
    if (lane == 0) red[w] = ps;
    __syncthreads();
    float partv = 2.0f * (red[0] + red[1] + red[2] + red[3]);  // = full sum - 8192
    float lp = __logf(partv);
    int b = blockIdx.x * 32 + (threadIdx.x & 31);
    if ((threadIdx.x >> 5) == 0) {
      float p = pij[b];
      out[b] = p * (__logf(p) + __logf(denomS[b]) + lp);
    }
  }
}

extern "C" void kernel_launch(void* const* d_in, const int* in_sizes, int n_in,
                              void* d_out, int out_size, void* d_ws, size_t ws_size,
                              hipStream_t stream) {
  const float* pij     = (const float*)d_in[0];
  const float* noise_f = (const float*)d_in[1];
  const float* noise_i = (const float*)d_in[2];
  const float* noise_j = (const float*)d_in[3];
  const float* logits  = (const float*)d_in[4];
  const float* topic_w = (const float*)d_in[5];
  const float* tb      = (const float*)d_in[6];
  const int*   ii      = (const int*)d_in[7];
  const int*   jj      = (const int*)d_in[8];
  float* out = (float*)d_out;

  char* ws = (char*)d_ws;
  float* partial     = (float*)ws;                               // 544 f32
  unsigned* c1       = (unsigned*)(ws + 4096);                   // barrier ctr 1
  unsigned* c2       = (unsigned*)(ws + 4096 + 128);             // barrier ctr 2
  unsigned short* xb = (unsigned short*)(ws + 8192);             // 8192*64 bf16 = 1 MB
  float* sq          = (float*)(ws + 8192 + 1048576);            // 8192 f32
  float* denomS      = (float*)(ws + 8192 + 1048576 + 32768);    // 8192 f32

  topicsne_fused<<<NBLOCKS, 256, 0, stream>>>(
      logits, noise_f, noise_i, noise_j, topic_w, tb, ii, jj, pij,
      xb, sq, denomS, partial, c1, c2, out);
}

// Round 8
// 112.117 us; speedup vs baseline: 1.3097x; 1.3097x over previous
//
#include <hip/hip_runtime.h>
#include <hip/hip_bf16.h>

// R8: revert to R6 exactly — the measured best (113.2 us, absmax 0.03125).
// R7's single-kernel fusion regressed +33.6 us: phase B at 4 waves/CU (half
// of pairwise's TLP) + __threadfence L2 writeback/invalidate at each grid
// barrier made all post-barrier reads L2-cold inside the kernel (FETCH_SIZE
// 4.3 -> 14.6 MB, hbm ~200 GB/s latency-bound). Node-merging has failed
// twice (R4 +31 us: single-block finalize tail; R7 +33.6 us); the remaining
// dispatch time is dominated by the harness's 256 MiB d_ws poison fill
// (~42 us at 81% of achievable HBM BW) + input-restore copies + graph-node
// overhead, none of which kernel code controls.

typedef short bf16x8 __attribute__((ext_vector_type(8)));
typedef float f32x4 __attribute__((ext_vector_type(4)));

__device__ __forceinline__ float wave_sum(float v) {
#pragma unroll
  for (int off = 32; off; off >>= 1) v += __shfl_xor(v, off);
  return v;
}

__device__ __forceinline__ unsigned short f2bf(float x) {  // RNE, finite inputs
  union { float f; unsigned u; } v; v.f = x;
  return (unsigned short)((v.u + 0x7fffu + ((v.u >> 16) & 1u)) >> 16);
}
__device__ __forceinline__ float bf2f(unsigned short h) {
  union { float f; unsigned u; } v; v.u = ((unsigned)h) << 16;
  return v.f;
}

// One wave: gumbel-softmax for 16 rows (K=128) -> A-fragments in-register ->
// acc += S @ W^T (16 MFMAs). lgp/nzp pre-offset to (row, part*8): lane
// (r,part) covers columns ks*32 + part*8 + j == exactly its A-fragment slices.
// Cross-lane traffic = softmax denominator only (shfl_xor; no LDS, no barrier).
__device__ __forceinline__ void gumbel_mfma(const float* __restrict__ lgp,
                                            const float* __restrict__ nzp,
                                            const bf16x8 Bf[4][4], f32x4 acc[4]) {
  float e[32];
  float ps = 0.0f;
#pragma unroll
  for (int ks = 0; ks < 4; ++ks) {
#pragma unroll
    for (int h = 0; h < 2; ++h) {
      float4 L = *(const float4*)(lgp + ks * 32 + h * 4);
      float4 U = *(const float4*)(nzp + ks * 32 + h * 4);
      float lv[4] = {L.x, L.y, L.z, L.w};
      float uv[4] = {U.x, U.y, U.z, U.w};
#pragma unroll
      for (int j = 0; j < 4; ++j) {
        float g = -__logf(-__logf(uv[j] + 1e-9f) + 1e-9f);
        float ev = __expf(lv[j] + g);
        e[ks * 8 + h * 4 + j] = ev;
        ps += ev;
      }
    }
  }
  ps += __shfl_xor(ps, 16);
  ps += __shfl_xor(ps, 32);
  float inv = __builtin_amdgcn_rcpf(ps);
#pragma unroll
  for (int ks = 0; ks < 4; ++ks) {
    union { bf16x8 v; unsigned short s[8]; } pk;
#pragma unroll
    for (int j = 0; j < 8; ++j) pk.s[j] = f2bf(e[ks * 8 + j] * inv);
#pragma unroll
    for (int nt = 0; nt < 4; ++nt)
      acc[nt] = __builtin_amdgcn_mfma_f32_16x16x32_bf16(pk.v, Bf[nt][ks], acc[nt], 0, 0, 0);
  }
}

// grid 256 x 256 threads. wid even -> x-type (16 rows of x), wid odd ->
// pair-type (xi,xj in-wave -> denom; bias cancels in the difference).
__global__ __launch_bounds__(256) void row_engine(
    const float* __restrict__ logits, const float* __restrict__ noise_f,
    const float* __restrict__ noise_i, const float* __restrict__ noise_j,
    const float* __restrict__ topic_w, const float* __restrict__ tb,
    const int* __restrict__ ii, const int* __restrict__ jj,
    unsigned short* __restrict__ xb, float* __restrict__ sq,
    float* __restrict__ denomS) {
  int w = threadIdx.x >> 6, lane = threadIdx.x & 63;
  int r = lane & 15, part = lane >> 4;
  int wid = blockIdx.x * 4 + w;

  // B fragments (held whole kernel): lane (r,part), step ks:
  // B[k = ks*32 + part*8 + j][n = nt*16 + r] = topic_w[n*128 + k].
  bf16x8 Bf[4][4];
#pragma unroll
  for (int nt = 0; nt < 4; ++nt) {
    const float* wp = topic_w + (nt * 16 + r) * 128 + part * 8;
#pragma unroll
    for (int ks = 0; ks < 4; ++ks) {
      float4 w0 = *(const float4*)(wp + ks * 32);
      float4 w1 = *(const float4*)(wp + ks * 32 + 4);
      union { bf16x8 v; unsigned short s[8]; } pk;
      pk.s[0] = f2bf(w0.x); pk.s[1] = f2bf(w0.y); pk.s[2] = f2bf(w0.z); pk.s[3] = f2bf(w0.w);
      pk.s[4] = f2bf(w1.x); pk.s[5] = f2bf(w1.y); pk.s[6] = f2bf(w1.z); pk.s[7] = f2bf(w1.w);
      Bf[nt][ks] = pk.v;
    }
  }
  int grp = wid >> 1;
  if ((wid & 1) == 0) {
    // x-type: rows g16..g16+15. C-layout: row m = part*4+g, col n = nt*16+r.
    int g16 = grp * 16;
    float tbv[4];
#pragma unroll
    for (int nt = 0; nt < 4; ++nt) tbv[nt] = tb[nt * 16 + r];
    f32x4 acc[4] = {};
    gumbel_mfma(logits + (g16 + r) * 128 + part * 8,
                noise_f + (g16 + r) * 128 + part * 8, Bf, acc);
    float sqp[4] = {0.f, 0.f, 0.f, 0.f};
#pragma unroll
    for (int nt = 0; nt < 4; ++nt)
#pragma unroll
      for (int g = 0; g < 4; ++g) {
        unsigned short hb = f2bf(acc[nt][g] + tbv[nt]);
        xb[(g16 + part * 4 + g) * 64 + nt * 16 + r] = hb;
        float xr = bf2f(hb);  // rounded value -> sq consistent with Gram dot
        sqp[g] += xr * xr;
      }
#pragma unroll
    for (int m = 1; m < 16; m <<= 1)
#pragma unroll
      for (int g = 0; g < 4; ++g) sqp[g] += __shfl_xor(sqp[g], m);
    if (r == 0) {
#pragma unroll
      for (int g = 0; g < 4; ++g) sq[g16 + part * 4 + g] = sqp[g];
    }
  } else {
    // pair-type: batch elems b0..b0+15; denom = 64 + ||xi-xj||^2 (fp32 diff).
    int b0 = grp * 16;
    int rowi = ii[b0 + r], rowj = jj[b0 + r];
    f32x4 ai[4] = {}, aj[4] = {};
    gumbel_mfma(logits + rowi * 128 + part * 8,
                noise_i + (b0 + r) * 128 + part * 8, Bf, ai);
    gumbel_mfma(logits + rowj * 128 + part * 8,
                noise_j + (b0 + r) * 128 + part * 8, Bf, aj);
    float dp[4] = {0.f, 0.f, 0.f, 0.f};
#pragma unroll
    for (int nt = 0; nt < 4; ++nt)
#pragma unroll
      for (int g = 0; g < 4; ++g) {
        float d = ai[nt][g] - aj[nt][g];
        dp[g] += d * d;
      }
#pragma unroll
    for (int m = 1; m < 16; m <<= 1)
#pragma unroll
      for (int g = 0; g < 4; ++g) dp[g] += __shfl_xor(dp[g], m);
    if (r == 0) {
#pragma unroll
      for (int g = 0; g < 4; ++g) denomS[b0 + part * 4 + g] = 64.0f + dp[g];
    }
  }
}

// Fat-block triangular pairwise, software-pipelined: 544 blocks, block =
// (row-band bi, chunk of <=4 column tiles). A-frags + m1 loaded once; B/nsq
// for tile bj+1 prefetched during tile bj's MFMA+epilogue (double buffer).
#define NPAIR_BLOCKS 544
__global__ __launch_bounds__(256) void pairwise(const unsigned short* __restrict__ xbp,
                                                const float* __restrict__ sq,
                                                float* __restrict__ partial) {
  __shared__ float red[4];
  int w = threadIdx.x >> 6, lane = threadIdx.x & 63;
  // decode blockIdx -> (bi, cj0): bi row-band, chunks of 4 over bj in [bi,63]
  int b = blockIdx.x, bi = 0, nch = 16;
  while (b >= nch) { b -= nch; ++bi; nch = (64 - bi + 3) >> 2; }
  int cj0 = bi + (b << 2);
  int wr = w >> 1, wc = w & 1;
  int R = bi * 128 + wr * 64;
  int r0 = lane & 15, kq = lane >> 4;

  bf16x8 A[4][2];
#pragma unroll
  for (int a = 0; a < 4; ++a)
#pragma unroll
    for (int s = 0; s < 2; ++s)
      A[a][s] = *(const bf16x8*)(xbp + (R + a * 16 + r0) * 64 + s * 32 + kq * 8);
  float m1[4][4];
#pragma unroll
  for (int a = 0; a < 4; ++a)
#pragma unroll
    for (int g = 0; g < 4; ++g) m1[a][g] = 1.0f + sq[R + a * 16 + kq * 4 + g];

  float local = 0.0f;
  int bjEnd = min(cj0 + 4, 64);
  int bj = cj0;
  if (cj0 == bi && wr > wc) ++bj;  // lower-left wave of the diag tile: skip it
  if (bj < bjEnd) {
    // prologue: load tile bj
    bf16x8 Bc[4][2];
    float nsqc[4];
    {
      int C = bj * 128 + wc * 64;
#pragma unroll
      for (int a = 0; a < 4; ++a)
#pragma unroll
        for (int s = 0; s < 2; ++s)
          Bc[a][s] = *(const bf16x8*)(xbp + (C + a * 16 + r0) * 64 + s * 32 + kq * 8);
#pragma unroll
      for (int q = 0; q < 4; ++q) nsqc[q] = sq[C + q * 16 + r0];
    }
    for (; bj < bjEnd; ++bj) {
      bool hasNext = (bj + 1) < bjEnd;
      bf16x8 Bn[4][2];
      float nsqn[4];
      if (hasNext) {  // issue next tile's loads before this tile's compute
        int Cn = (bj + 1) * 128 + wc * 64;
#pragma unroll
        for (int a = 0; a < 4; ++a)
#pragma unroll
          for (int s = 0; s < 2; ++s)
            Bn[a][s] = *(const bf16x8*)(xbp + (Cn + a * 16 + r0) * 64 + s * 32 + kq * 8);
#pragma unroll
        for (int q = 0; q < 4; ++q) nsqn[q] = sq[Cn + q * 16 + r0];
      }

      f32x4 acc[4][4] = {};
#pragma unroll
      for (int a = 0; a < 4; ++a)
#pragma unroll
        for (int q = 0; q < 4; ++q) {
          acc[a][q] = __builtin_amdgcn_mfma_f32_16x16x32_bf16(A[a][0], Bc[q][0], acc[a][q], 0, 0, 0);
          acc[a][q] = __builtin_amdgcn_mfma_f32_16x16x32_bf16(A[a][1], Bc[q][1], acc[a][q], 0, 0, 0);
        }

      if (bj == bi && wr == wc) {  // tile straddling the diagonal: r<c only
#pragma unroll
        for (int a = 0; a < 4; ++a)
#pragma unroll
          for (int q = 0; q < 4; ++q)
#pragma unroll
            for (int g = 0; g < 4; ++g) {
              float d = fmaf(-2.0f, acc[a][q][g], m1[a][g] + nsqc[q]);
              int rl = a * 16 + kq * 4 + g, cl = q * 16 + r0;
              local += (rl < cl) ? __builtin_amdgcn_rcpf(d) : 0.0f;
            }
      } else {
#pragma unroll
        for (int a = 0; a < 4; ++a)
#pragma unroll
          for (int q = 0; q < 4; ++q)
#pragma unroll
            for (int g = 0; g < 4; ++g) {
              float d = fmaf(-2.0f, acc[a][q][g], m1[a][g] + nsqc[q]);
              local += __builtin_amdgcn_rcpf(d);
            }
      }

      if (hasNext) {
#pragma unroll
        for (int a = 0; a < 4; ++a)
#pragma unroll
          for (int s = 0; s < 2; ++s) Bc[a][s] = Bn[a][s];
#pragma unroll
        for (int q = 0; q < 4; ++q) nsqc[q] = nsqn[q];
      }
    }
  }
  local = wave_sum(local);
  if (lane == 0) red[w] = local;
  __syncthreads();
  if (threadIdx.x == 0) partial[blockIdx.x] = red[0] + red[1] + red[2] + red[3];
}

// part = 2 * sum_{m<n} rcp = (ref's full sum incl. diagonal) - 8192 exactly.
__global__ __launch_bounds__(256) void finalize(const float* __restrict__ pij,
                                                const float* __restrict__ denomS,
                                                const float* __restrict__ partial,
                                                float* __restrict__ out) {
  __shared__ float red[4];
  int tid = threadIdx.x, w = tid >> 6, lane = tid & 63;
  float ps = 0.0f;
  for (int k = tid; k < NPAIR_BLOCKS; k += 256) ps += partial[k];
  ps = wave_sum(ps);
  if (lane == 0) red[w] = ps;
  __syncthreads();
  float part = 2.0f * (red[0] + red[1] + red[2] + red[3]);
  int b = blockIdx.x * 256 + tid;
  float p = pij[b];
  out[b] = p * (__logf(p) + __logf(denomS[b]) + __logf(part));
}

extern "C" void kernel_launch(void* const* d_in, const int* in_sizes, int n_in,
                              void* d_out, int out_size, void* d_ws, size_t ws_size,
                              hipStream_t stream) {
  const float* pij     = (const float*)d_in[0];
  const float* noise_f = (const float*)d_in[1];
  const float* noise_i = (const float*)d_in[2];
  const float* noise_j = (const float*)d_in[3];
  const float* logits  = (const float*)d_in[4];
  const float* topic_w = (const float*)d_in[5];
  const float* tb      = (const float*)d_in[6];
  const int*   ii      = (const int*)d_in[7];
  const int*   jj      = (const int*)d_in[8];
  float* out = (float*)d_out;

  char* ws = (char*)d_ws;
  float* partial     = (float*)ws;                               // 544 f32
  unsigned short* xb = (unsigned short*)(ws + 8192);             // 8192*64 bf16 = 1 MB
  float* sq          = (float*)(ws + 8192 + 1048576);            // 8192 f32
  float* denomS      = (float*)(ws + 8192 + 1048576 + 32768);    // 8192 f32

  row_engine<<<256, 256, 0, stream>>>(logits, noise_f, noise_i, noise_j,
                                      topic_w, tb, ii, jj, xb, sq, denomS);
  pairwise<<<NPAIR_BLOCKS, 256, 0, stream>>>(xb, sq, partial);
  finalize<<<32, 256, 0, stream>>>(pij, denomS, partial, out);
}